// Round 11
// baseline (905.103 us; speedup 1.0000x reference)
//
#include <hip/hip_runtime.h>
#include <hip/hip_bf16.h>

typedef __hip_bfloat16 bf16;
typedef __attribute__((ext_vector_type(8))) short short8;
typedef __attribute__((ext_vector_type(4))) float f32x4;
typedef unsigned short u16;
#define BF2F(x) __bfloat162float(x)

__device__ __forceinline__ u16 f2bfbits(float v) {
  bf16 h = __float2bfloat16(v);
  return *(u16*)&h;
}
__device__ __forceinline__ float bfbits2f(u16 u) {
  bf16 h; *(u16*)&h = u;
  return BF2F(h);
}
__device__ __forceinline__ void splitbf(float v, u16& hi, u16& lo) {
  hi = f2bfbits(v);
  lo = f2bfbits(v - bfbits2f(hi));
}

union VecU {
  u16 u[8];
  short8 s;
};

// ---------------- NCHW(f32) -> NHWC(f32) ----------------
__global__ void nchw2nhwc_kernel(const float* __restrict__ in, float* __restrict__ out,
                                 int B, int C, int HW) {
  int i = blockIdx.x * blockDim.x + threadIdx.x;
  int total = B * C * HW;
  if (i >= total) return;
  int c = i % C; int p = (i / C) % HW; int b = i / (C * HW);
  out[i] = in[((size_t)b * C + c) * HW + p];
}

// ------- ALL conv weights -> bf16 hi/lo [co][k2*C+ci], one launch, coalesced -------
template<int C, int Kp>
__device__ __forceinline__ void wtc_pair(const float* __restrict__ w, u16* __restrict__ Wh,
                                         u16* __restrict__ Wl, int rel) {
  int co = rel / C, ci = rel % C;
  const float* src = w + ((size_t)co * C + ci) * 9;
  float v[9];
#pragma unroll
  for (int k2 = 0; k2 < 9; ++k2) v[k2] = src[k2];
  size_t ob = (size_t)co * Kp + ci;
#pragma unroll
  for (int k2 = 0; k2 < 9; ++k2) {
    u16 hh, ll; splitbf(v[k2], hh, ll);
    Wh[ob + (size_t)k2 * C] = hh;
    Wl[ob + (size_t)k2 * C] = ll;
  }
}

#define PAIR_TOTAL 1634496
#define PAD_TOTAL 320   // layer-0: 64 rows x (32-27) pad elems

__global__ void wtc_all_v2(
    const float* w0, const float* w1, const float* w2, const float* w3,
    const float* w4, const float* w5, const float* w6, const float* w7,
    const float* w8, const float* w9, const float* w10, const float* w11,
    const float* w12, u16* __restrict__ Wh, u16* __restrict__ Wl) {
  int i = blockIdx.x * blockDim.x + threadIdx.x;
  if (i >= PAIR_TOTAL + PAD_TOTAL) return;
  if (i >= PAIR_TOTAL) {  // zero layer-0 pad: Wh[co*32 + k], k in [27,32)
    int t = i - PAIR_TOTAL;
    int co = t / 5, k = 27 + t % 5;
    int o = co * 32 + k;
    Wh[o] = 0; Wl[o] = 0;
    return;
  }
  if      (i < 192)     wtc_pair<3, 32>(w0, Wh + 0, Wl + 0, i);
  else if (i < 4288)    wtc_pair<64, 576>(w1, Wh + 2048, Wl + 2048, i - 192);
  else if (i < 12480)   wtc_pair<64, 576>(w2, Wh + 38912, Wl + 38912, i - 4288);
  else if (i < 28864)   wtc_pair<128, 1152>(w3, Wh + 112640, Wl + 112640, i - 12480);
  else if (i < 61632)   wtc_pair<128, 1152>(w4, Wh + 260096, Wl + 260096, i - 28864);
  else if (i < 127168)  wtc_pair<256, 2304>(w5, Wh + 555008, Wl + 555008, i - 61632);
  else if (i < 192704)  wtc_pair<256, 2304>(w6, Wh + 1144832, Wl + 1144832, i - 127168);
  else if (i < 323776)  wtc_pair<256, 2304>(w7, Wh + 1734656, Wl + 1734656, i - 192704);
  else if (i < 585920)  wtc_pair<512, 4608>(w8, Wh + 2914304, Wl + 2914304, i - 323776);
  else if (i < 848064)  wtc_pair<512, 4608>(w9, Wh + 5273600, Wl + 5273600, i - 585920);
  else if (i < 1110208) wtc_pair<512, 4608>(w10, Wh + 7632896, Wl + 7632896, i - 848064);
  else if (i < 1372352) wtc_pair<512, 4608>(w11, Wh + 9992192, Wl + 9992192, i - 1110208);
  else                  wtc_pair<512, 4608>(w12, Wh + 12351488, Wl + 12351488, i - 1372352);
}

// ------- fp32 activations -> bf16 hi/lo pair -------
__global__ void act_convert(const float* __restrict__ x,
                            u16* __restrict__ Ah, u16* __restrict__ Al, int total) {
  int i = blockIdx.x * blockDim.x + threadIdx.x;
  if (i >= total) return;
  u16 hh, ll; splitbf(x[i], hh, ll);
  Ah[i] = hh; Al[i] = ll;
}

// ------- deformable sampling: thread = (pixel, k2, 8-channel chunk) -------
__global__ __launch_bounds__(256) void deform_sample_v3(
    const float* __restrict__ act, const float* __restrict__ stp, int bnmode,
    const float* __restrict__ off, u16* __restrict__ Sh, u16* __restrict__ Sl,
    int m0, int Mc, int B, int H, int W, int C, int Kp) {
  int i = blockIdx.x * blockDim.x + threadIdx.x;
  int c8n = C >> 3;
  int total = Mc * 9 * c8n;
  if (i >= total) return;
  int c8 = i % c8n;
  int t = i / c8n;
  int k2 = t % 9;
  int ml = t / 9;
  int m = m0 + ml;
  int HW = H * W;
  int b = m / HW; int p = m - b * HW; int y = p / W; int x = p - y * W;
  size_t ob = (size_t)b * 18 * HW + p;
  float dy = off[ob + (size_t)(2 * k2) * HW];
  float dx = off[ob + (size_t)(2 * k2 + 1) * HW];
  float py = (float)(y + k2 / 3 - 1) + dy;
  float px = (float)(x + k2 % 3 - 1) + dx;
  float y0f = floorf(py), x0f = floorf(px);
  float wy = py - y0f, wx = px - x0f;
  int iy0 = (int)y0f, ix0 = (int)x0f;
  int iy1 = iy0 + 1, ix1 = ix0 + 1;
  float w00 = (1.f - wy) * (1.f - wx), w01 = (1.f - wy) * wx;
  float w10 = wy * (1.f - wx), w11 = wy * wx;
  if (iy0 < 0 || iy0 >= H) { w00 = 0.f; w01 = 0.f; }
  if (iy1 < 0 || iy1 >= H) { w10 = 0.f; w11 = 0.f; }
  if (ix0 < 0 || ix0 >= W) { w00 = 0.f; w10 = 0.f; }
  if (ix1 < 0 || ix1 >= W) { w01 = 0.f; w11 = 0.f; }
  int cy0 = min(max(iy0, 0), H - 1), cy1 = min(max(iy1, 0), H - 1);
  int cx0 = min(max(ix0, 0), W - 1), cx1 = min(max(ix1, 0), W - 1);
  int c = c8 << 3;
  size_t rowb = (size_t)b * HW;
  const float* p00 = act + (rowb + cy0 * W + cx0) * C + c;
  const float* p01 = act + (rowb + cy0 * W + cx1) * C + c;
  const float* p10 = act + (rowb + cy1 * W + cx0) * C + c;
  const float* p11 = act + (rowb + cy1 * W + cx1) * C + c;
  float4 a00 = *(const float4*)p00, b00 = *(const float4*)(p00 + 4);
  float4 a01 = *(const float4*)p01, b01 = *(const float4*)(p01 + 4);
  float4 a10 = *(const float4*)p10, b10 = *(const float4*)(p10 + 4);
  float4 a11 = *(const float4*)p11, b11 = *(const float4*)(p11 + 4);
  float v00[8] = {a00.x, a00.y, a00.z, a00.w, b00.x, b00.y, b00.z, b00.w};
  float v01[8] = {a01.x, a01.y, a01.z, a01.w, b01.x, b01.y, b01.z, b01.w};
  float v10[8] = {a10.x, a10.y, a10.z, a10.w, b10.x, b10.y, b10.z, b10.w};
  float v11[8] = {a11.x, a11.y, a11.z, a11.w, b11.x, b11.y, b11.z, b11.w};
  if (bnmode) {
    float4 s0 = *(const float4*)(stp + c), s1 = *(const float4*)(stp + c + 4);
    float4 h0 = *(const float4*)(stp + 512 + c), h1 = *(const float4*)(stp + 512 + c + 4);
    float sc[8] = {s0.x, s0.y, s0.z, s0.w, s1.x, s1.y, s1.z, s1.w};
    float sh[8] = {h0.x, h0.y, h0.z, h0.w, h1.x, h1.y, h1.z, h1.w};
#pragma unroll
    for (int j = 0; j < 8; ++j) {
      v00[j] = fmaxf(v00[j] * sc[j] + sh[j], 0.f);
      v01[j] = fmaxf(v01[j] * sc[j] + sh[j], 0.f);
      v10[j] = fmaxf(v10[j] * sc[j] + sh[j], 0.f);
      v11[j] = fmaxf(v11[j] * sc[j] + sh[j], 0.f);
    }
  }
  VecU uh, ul;
#pragma unroll
  for (int j = 0; j < 8; ++j) {
    float r = w00 * v00[j] + w01 * v01[j] + w10 * v10[j] + w11 * v11[j];
    splitbf(r, uh.u[j], ul.u[j]);
  }
  size_t base = (size_t)ml * Kp + (size_t)k2 * C + c;
  *(short8*)(Sh + base) = uh.s;
  *(short8*)(Sl + base) = ul.s;
}

// ------- scalar variant for layer 0 (C=3, K=27, Kp=32; covers zero padding) -------
__global__ __launch_bounds__(256) void deform_sample_scalar(
    const float* __restrict__ act, const float* __restrict__ off,
    u16* __restrict__ Sh, u16* __restrict__ Sl,
    int m0, int Mc, int B, int H, int W, int C, int Kp) {
  int i = blockIdx.x * blockDim.x + threadIdx.x;
  int total = Mc * Kp;
  if (i >= total) return;
  int kp = i % Kp;
  int ml = i / Kp;
  float val = 0.f;
  int K = 9 * C;
  if (kp < K) {
    int c = kp % C; int k2 = kp / C;
    int m = m0 + ml;
    int HW = H * W;
    int b = m / HW; int p = m - b * HW; int y = p / W; int x = p - y * W;
    size_t ob = (size_t)b * 18 * HW + p;
    float dy = off[ob + (size_t)(2 * k2) * HW];
    float dx = off[ob + (size_t)(2 * k2 + 1) * HW];
    float py = (float)(y + k2 / 3 - 1) + dy;
    float px = (float)(x + k2 % 3 - 1) + dx;
    float y0f = floorf(py), x0f = floorf(px);
    float wy = py - y0f, wx = px - x0f;
    int iy0 = (int)y0f, ix0 = (int)x0f;
    int iy1 = iy0 + 1, ix1 = ix0 + 1;
    float w00 = (1.f - wy) * (1.f - wx), w01 = (1.f - wy) * wx;
    float w10 = wy * (1.f - wx), w11 = wy * wx;
    if (iy0 < 0 || iy0 >= H) { w00 = 0.f; w01 = 0.f; }
    if (iy1 < 0 || iy1 >= H) { w10 = 0.f; w11 = 0.f; }
    if (ix0 < 0 || ix0 >= W) { w00 = 0.f; w10 = 0.f; }
    if (ix1 < 0 || ix1 >= W) { w01 = 0.f; w11 = 0.f; }
    int cy0 = min(max(iy0, 0), H - 1), cy1 = min(max(iy1, 0), H - 1);
    int cx0 = min(max(ix0, 0), W - 1), cx1 = min(max(ix1, 0), W - 1);
    size_t rowb = (size_t)b * HW;
    float v00 = act[(rowb + cy0 * W + cx0) * C + c];
    float v01 = act[(rowb + cy0 * W + cx1) * C + c];
    float v10 = act[(rowb + cy1 * W + cx0) * C + c];
    float v11 = act[(rowb + cy1 * W + cx1) * C + c];
    val = w00 * v00 + w01 * v01 + w10 * v10 + w11 * v11;
  }
  u16 hh, ll; splitbf(val, hh, ll);
  size_t base = (size_t)ml * Kp + kp;
  Sh[base] = hh; Sl[base] = ll;
}

// ---------------- 4-wave tiled MFMA GEMM (bf16x3), 64x64 tile, dbuf LDS ----------------
// DEPTH-2 register pipeline: loads for step i+2 issued at step i; ds_write of step i+1's
// data (issued a full step earlier -> vmcnt satisfied) happens after step i's compute.
#define LDA 40  // u16 units per LDS row (32 data + 8 pad -> 2-way bank alias only)

struct StageT { short8 a, b, c, d; };

__global__ __launch_bounds__(256) void mfma_gemm_tiled(
    const u16* __restrict__ Ah, const u16* __restrict__ Al,
    const u16* __restrict__ Bh, const u16* __restrict__ Bl,
    float* __restrict__ Cf, int M, int N, int Kp, int kPerZ, int splitMode) {
  __shared__ __align__(16) u16 lds[2 * 4 * 64 * LDA];
  const int TS = 64 * LDA;
  const int BS = 4 * TS;
  int tid = threadIdx.x;
  int lane = tid & 63, wave = tid >> 6;
  int l15 = lane & 15, quad = lane >> 4;
  int wr = wave >> 1, wc = wave & 1;
  int m0 = blockIdx.x * 64, n0 = blockIdx.y * 64;
  int kStart = blockIdx.z * kPerZ;
  int kEnd = min(Kp, kStart + kPerZ);
  int nSteps = (kEnd - kStart) >> 5;

  int sr = tid >> 2, sc = (tid & 3) << 3;
  const u16* gAh = Ah + (size_t)(m0 + sr) * Kp + kStart + sc;
  const u16* gAl = Al + (size_t)(m0 + sr) * Kp + kStart + sc;
  const u16* gBh = Bh + (size_t)(n0 + sr) * Kp + kStart + sc;
  const u16* gBl = Bl + (size_t)(n0 + sr) * Kp + kStart + sc;
  int soff = sr * LDA + sc;

  f32x4 z4 = {0.f, 0.f, 0.f, 0.f};
  f32x4 acc00 = z4, acc01 = z4, acc10 = z4, acc11 = z4;

  auto loadStage = [&](int i, StageT& s) {
    int kn = i << 5;
    s.a = *(const short8*)(gAh + kn);
    s.b = *(const short8*)(gAl + kn);
    s.c = *(const short8*)(gBh + kn);
    s.d = *(const short8*)(gBl + kn);
  };
  auto writeStage = [&](int buf, const StageT& s) {
    int ob = buf * BS;
    *(short8*)&lds[ob + 0 * TS + soff] = s.a;
    *(short8*)&lds[ob + 1 * TS + soff] = s.b;
    *(short8*)&lds[ob + 2 * TS + soff] = s.c;
    *(short8*)&lds[ob + 3 * TS + soff] = s.d;
  };

  int raoff = (wr * 32 + l15) * LDA + quad * 8;
  int rboff = (wc * 32 + l15) * LDA + quad * 8;
  auto compute = [&](int cb) {
    short8 ah0 = *(const short8*)&lds[cb + 0 * TS + raoff];
    short8 ah1 = *(const short8*)&lds[cb + 0 * TS + raoff + 16 * LDA];
    short8 al0 = *(const short8*)&lds[cb + 1 * TS + raoff];
    short8 al1 = *(const short8*)&lds[cb + 1 * TS + raoff + 16 * LDA];
    short8 bh0 = *(const short8*)&lds[cb + 2 * TS + rboff];
    short8 bh1 = *(const short8*)&lds[cb + 2 * TS + rboff + 16 * LDA];
    short8 bl0 = *(const short8*)&lds[cb + 3 * TS + rboff];
    short8 bl1 = *(const short8*)&lds[cb + 3 * TS + rboff + 16 * LDA];
    acc00 = __builtin_amdgcn_mfma_f32_16x16x32_bf16(ah0, bh0, acc00, 0, 0, 0);
    acc01 = __builtin_amdgcn_mfma_f32_16x16x32_bf16(ah0, bh1, acc01, 0, 0, 0);
    acc10 = __builtin_amdgcn_mfma_f32_16x16x32_bf16(ah1, bh0, acc10, 0, 0, 0);
    acc11 = __builtin_amdgcn_mfma_f32_16x16x32_bf16(ah1, bh1, acc11, 0, 0, 0);
    acc00 = __builtin_amdgcn_mfma_f32_16x16x32_bf16(ah0, bl0, acc00, 0, 0, 0);
    acc01 = __builtin_amdgcn_mfma_f32_16x16x32_bf16(ah0, bl1, acc01, 0, 0, 0);
    acc10 = __builtin_amdgcn_mfma_f32_16x16x32_bf16(ah1, bl0, acc10, 0, 0, 0);
    acc11 = __builtin_amdgcn_mfma_f32_16x16x32_bf16(ah1, bl1, acc11, 0, 0, 0);
    acc00 = __builtin_amdgcn_mfma_f32_16x16x32_bf16(al0, bh0, acc00, 0, 0, 0);
    acc01 = __builtin_amdgcn_mfma_f32_16x16x32_bf16(al0, bh1, acc01, 0, 0, 0);
    acc10 = __builtin_amdgcn_mfma_f32_16x16x32_bf16(al1, bh0, acc10, 0, 0, 0);
    acc11 = __builtin_amdgcn_mfma_f32_16x16x32_bf16(al1, bh1, acc11, 0, 0, 0);
  };

  StageT s0, s1;
  {  // prologue: stage step 0 directly into buffer 0; prefetch step 1 into s0
    StageT t;
    loadStage(0, t);
    writeStage(0, t);
    if (nSteps > 1) loadStage(1, s0);
  }
  __syncthreads();

  int i = 0;
  while (true) {
    if (i + 2 < nSteps) loadStage(i + 2, s1);
    compute((i & 1) * BS);
    ++i;
    if (i >= nSteps) break;
    writeStage(i & 1, s0);   // s0 issued a full step ago -> no vmcnt stall
    __syncthreads();
    s0 = s1;                 // rotate (reg moves, ~16 v_mov)
  }

  float* out = Cf + (splitMode ? (size_t)blockIdx.z * M * N : (size_t)0);
  f32x4 av[2][2] = {{acc00, acc01}, {acc10, acc11}};
#pragma unroll
  for (int t = 0; t < 2; ++t) {
    int mB = m0 + wr * 32 + t * 16 + (quad << 2);
#pragma unroll
    for (int u = 0; u < 2; ++u) {
      int n = n0 + wc * 32 + u * 16 + l15;
      f32x4 a = av[t][u];
#pragma unroll
      for (int reg = 0; reg < 4; ++reg) {
        int m = mB + reg;
        out[(size_t)m * N + n] = a[reg];
      }
    }
  }
}

// ---------------- FUSED deformable-sample + GEMM (used only when gy==1 && zs==1) ----------
// A-tile is sampled on the fly (bilinear + optional BN+ReLU on prev act), no S buffer.
// Requires: C power of 2 (>=64), Kp = 9*C, M,N multiples of 64, H=W power of 2.
__global__ __launch_bounds__(256) void mfma_gemm_fused(
    const float* __restrict__ act, const float* __restrict__ stp, int bnmode,
    const float* __restrict__ off,
    const u16* __restrict__ Bh, const u16* __restrict__ Bl,
    float* __restrict__ Cf, int M, int N, int Kp, int kPerZ, int splitMode,
    int H, int W, int C, int lc, int lhw, int lw) {
  __shared__ __align__(16) u16 lds[2 * 4 * 64 * LDA];
  const int TS = 64 * LDA;
  const int BS = 4 * TS;
  int tid = threadIdx.x;
  int lane = tid & 63, wave = tid >> 6;
  int l15 = lane & 15, quad = lane >> 4;
  int wr = wave >> 1, wc = wave & 1;
  int m0 = blockIdx.x * 64, n0 = blockIdx.y * 64;
  int kStart = blockIdx.z * kPerZ;
  int kEnd = min(Kp, kStart + kPerZ);
  int nSteps = (kEnd - kStart) >> 5;

  int sr = tid >> 2, sc = (tid & 3) << 3;
  int HWv = H * W;
  int m = m0 + sr;
  int b = m >> lhw; int p = m & (HWv - 1); int y = p >> lw; int x = p & (W - 1);
  size_t obase = (size_t)b * 18 * HWv + p;
  size_t rowb = (size_t)b * HWv;
  const u16* gBh = Bh + (size_t)(n0 + sr) * Kp + kStart + sc;
  const u16* gBl = Bl + (size_t)(n0 + sr) * Kp + kStart + sc;
  int soff = sr * LDA + sc;

  f32x4 z4 = {0.f, 0.f, 0.f, 0.f};
  f32x4 acc00 = z4, acc01 = z4, acc10 = z4, acc11 = z4;

  auto SAMPLE = [&](int kk, short8& uh8, short8& ul8) {
    int k2 = kk >> lc;
    int ci = kk & (C - 1);
    float dy = off[obase + (size_t)(2 * k2) * HWv];
    float dx = off[obase + (size_t)(2 * k2 + 1) * HWv];
    float py = (float)(y + k2 / 3 - 1) + dy;
    float px = (float)(x + k2 % 3 - 1) + dx;
    float y0f = floorf(py), x0f = floorf(px);
    float wy = py - y0f, wx = px - x0f;
    int iy0 = (int)y0f, ix0 = (int)x0f;
    int iy1 = iy0 + 1, ix1 = ix0 + 1;
    float w00 = (1.f - wy) * (1.f - wx), w01 = (1.f - wy) * wx;
    float w10 = wy * (1.f - wx), w11 = wy * wx;
    if (iy0 < 0 || iy0 >= H) { w00 = 0.f; w01 = 0.f; }
    if (iy1 < 0 || iy1 >= H) { w10 = 0.f; w11 = 0.f; }
    if (ix0 < 0 || ix0 >= W) { w00 = 0.f; w10 = 0.f; }
    if (ix1 < 0 || ix1 >= W) { w01 = 0.f; w11 = 0.f; }
    int cy0 = min(max(iy0, 0), H - 1), cy1 = min(max(iy1, 0), H - 1);
    int cx0 = min(max(ix0, 0), W - 1), cx1 = min(max(ix1, 0), W - 1);
    const float* p00 = act + (rowb + cy0 * W + cx0) * C + ci;
    const float* p01 = act + (rowb + cy0 * W + cx1) * C + ci;
    const float* p10 = act + (rowb + cy1 * W + cx0) * C + ci;
    const float* p11 = act + (rowb + cy1 * W + cx1) * C + ci;
    float4 a00 = *(const float4*)p00, b00 = *(const float4*)(p00 + 4);
    float4 a01 = *(const float4*)p01, b01 = *(const float4*)(p01 + 4);
    float4 a10 = *(const float4*)p10, b10 = *(const float4*)(p10 + 4);
    float4 a11 = *(const float4*)p11, b11 = *(const float4*)(p11 + 4);
    float v00[8] = {a00.x, a00.y, a00.z, a00.w, b00.x, b00.y, b00.z, b00.w};
    float v01[8] = {a01.x, a01.y, a01.z, a01.w, b01.x, b01.y, b01.z, b01.w};
    float v10[8] = {a10.x, a10.y, a10.z, a10.w, b10.x, b10.y, b10.z, b10.w};
    float v11[8] = {a11.x, a11.y, a11.z, a11.w, b11.x, b11.y, b11.z, b11.w};
    if (bnmode) {
      float4 s0 = *(const float4*)(stp + ci), s1 = *(const float4*)(stp + ci + 4);
      float4 h0 = *(const float4*)(stp + 512 + ci), h1 = *(const float4*)(stp + 512 + ci + 4);
      float scv[8] = {s0.x, s0.y, s0.z, s0.w, s1.x, s1.y, s1.z, s1.w};
      float shv[8] = {h0.x, h0.y, h0.z, h0.w, h1.x, h1.y, h1.z, h1.w};
#pragma unroll
      for (int j = 0; j < 8; ++j) {
        v00[j] = fmaxf(v00[j] * scv[j] + shv[j], 0.f);
        v01[j] = fmaxf(v01[j] * scv[j] + shv[j], 0.f);
        v10[j] = fmaxf(v10[j] * scv[j] + shv[j], 0.f);
        v11[j] = fmaxf(v11[j] * scv[j] + shv[j], 0.f);
      }
    }
    VecU uh, ul;
#pragma unroll
    for (int j = 0; j < 8; ++j) {
      float r = w00 * v00[j] + w01 * v01[j] + w10 * v10[j] + w11 * v11[j];
      splitbf(r, uh.u[j], ul.u[j]);
    }
    uh8 = uh.s; ul8 = ul.s;
  };

  {  // prologue
    short8 sa, sb;
    SAMPLE(kStart + sc, sa, sb);
    short8 c = *(const short8*)gBh;
    short8 d = *(const short8*)gBl;
    *(short8*)&lds[0 * TS + soff] = sa;
    *(short8*)&lds[1 * TS + soff] = sb;
    *(short8*)&lds[2 * TS + soff] = c;
    *(short8*)&lds[3 * TS + soff] = d;
  }
  __syncthreads();

  int raoff = (wr * 32 + l15) * LDA + quad * 8;
  int rboff = (wc * 32 + l15) * LDA + quad * 8;

  for (int i = 0; i < nSteps; ++i) {
    int cb = (i & 1) * BS;
    bool hasNext = (i + 1 < nSteps);
    short8 nA, nB, nC, nD;
    if (hasNext) {
      int kn = (i + 1) << 5;
      SAMPLE(kStart + kn + sc, nA, nB);
      nC = *(const short8*)(gBh + kn);
      nD = *(const short8*)(gBl + kn);
    }
    short8 ah0 = *(const short8*)&lds[cb + 0 * TS + raoff];
    short8 ah1 = *(const short8*)&lds[cb + 0 * TS + raoff + 16 * LDA];
    short8 al0 = *(const short8*)&lds[cb + 1 * TS + raoff];
    short8 al1 = *(const short8*)&lds[cb + 1 * TS + raoff + 16 * LDA];
    short8 bh0 = *(const short8*)&lds[cb + 2 * TS + rboff];
    short8 bh1 = *(const short8*)&lds[cb + 2 * TS + rboff + 16 * LDA];
    short8 bl0 = *(const short8*)&lds[cb + 3 * TS + rboff];
    short8 bl1 = *(const short8*)&lds[cb + 3 * TS + rboff + 16 * LDA];
    acc00 = __builtin_amdgcn_mfma_f32_16x16x32_bf16(ah0, bh0, acc00, 0, 0, 0);
    acc01 = __builtin_amdgcn_mfma_f32_16x16x32_bf16(ah0, bh1, acc01, 0, 0, 0);
    acc10 = __builtin_amdgcn_mfma_f32_16x16x32_bf16(ah1, bh0, acc10, 0, 0, 0);
    acc11 = __builtin_amdgcn_mfma_f32_16x16x32_bf16(ah1, bh1, acc11, 0, 0, 0);
    acc00 = __builtin_amdgcn_mfma_f32_16x16x32_bf16(ah0, bl0, acc00, 0, 0, 0);
    acc01 = __builtin_amdgcn_mfma_f32_16x16x32_bf16(ah0, bl1, acc01, 0, 0, 0);
    acc10 = __builtin_amdgcn_mfma_f32_16x16x32_bf16(ah1, bl0, acc10, 0, 0, 0);
    acc11 = __builtin_amdgcn_mfma_f32_16x16x32_bf16(ah1, bl1, acc11, 0, 0, 0);
    acc00 = __builtin_amdgcn_mfma_f32_16x16x32_bf16(al0, bh0, acc00, 0, 0, 0);
    acc01 = __builtin_amdgcn_mfma_f32_16x16x32_bf16(al0, bh1, acc01, 0, 0, 0);
    acc10 = __builtin_amdgcn_mfma_f32_16x16x32_bf16(al1, bh0, acc10, 0, 0, 0);
    acc11 = __builtin_amdgcn_mfma_f32_16x16x32_bf16(al1, bh1, acc11, 0, 0, 0);
    if (hasNext) {
      int ob = cb ^ BS;
      *(short8*)&lds[ob + 0 * TS + soff] = nA;
      *(short8*)&lds[ob + 1 * TS + soff] = nB;
      *(short8*)&lds[ob + 2 * TS + soff] = nC;
      *(short8*)&lds[ob + 3 * TS + soff] = nD;
      __syncthreads();
    }
  }

  float* out = Cf + (splitMode ? (size_t)blockIdx.z * M * N : (size_t)0);
  f32x4 av[2][2] = {{acc00, acc01}, {acc10, acc11}};
#pragma unroll
  for (int t = 0; t < 2; ++t) {
    int mB = m0 + wr * 32 + t * 16 + (quad << 2);
#pragma unroll
    for (int u = 0; u < 2; ++u) {
      int n = n0 + wc * 32 + u * 16 + l15;
      f32x4 a = av[t][u];
#pragma unroll
      for (int reg = 0; reg < 4; ++reg) {
        int mm = mB + reg;
        out[(size_t)mm * N + n] = a[reg];
      }
    }
  }
}

// ---------------- FC: 4-wave, M=32 fixed, B fp32 staged->bf16 pair in LDS ----------------
#define LDAF 40

__global__ __launch_bounds__(256) void mfma_gemm_fc4(
    const u16* __restrict__ Ah, const u16* __restrict__ Al,
    const float* __restrict__ Bw, float* __restrict__ Cf,
    int N, int K, int kPerZ) {
  __shared__ __align__(16) u16 sB[2][2][64 * LDAF];
  int tid = threadIdx.x;
  int lane = tid & 63, wave = tid >> 6;
  int l15 = lane & 15, quad = lane >> 4;
  int wm = wave >> 1, wn = wave & 1;
  int n0 = blockIdx.y * 64;
  int kStart = blockIdx.z * kPerZ;
  int kEnd = min(K, kStart + kPerZ);
  int nSteps = (kEnd - kStart) >> 5;

  int sr = tid >> 2, sc = (tid & 3) << 3;
  int gn = n0 + sr; if (gn >= N) gn = 0;
  const float* gB = Bw + (size_t)gn * K + kStart + sc;
  int soff = sr * LDAF + sc;

  const u16* pa = Ah + (size_t)(wm * 16 + l15) * K + kStart + (quad << 3);
  const u16* qa = Al + (size_t)(wm * 16 + l15) * K + kStart + (quad << 3);

  f32x4 z4 = {0.f, 0.f, 0.f, 0.f};
  f32x4 acc0 = z4, acc1 = z4;

  {
    float4 x0 = *(const float4*)gB;
    float4 x1 = *(const float4*)(gB + 4);
    float f[8] = {x0.x, x0.y, x0.z, x0.w, x1.x, x1.y, x1.z, x1.w};
    VecU uh, ul;
#pragma unroll
    for (int j = 0; j < 8; ++j) splitbf(f[j], uh.u[j], ul.u[j]);
    *(short8*)&sB[0][0][soff] = uh.s;
    *(short8*)&sB[0][1][soff] = ul.s;
  }
  __syncthreads();

  int rb0 = (wn * 32 + l15) * LDAF + (quad << 3);
  int rb1 = (wn * 32 + 16 + l15) * LDAF + (quad << 3);

  for (int i = 0; i < nSteps; ++i) {
    int cb = i & 1;
    bool hasNext = (i + 1 < nSteps);
    float4 x0, x1;
    if (hasNext) {
      int kn = (i + 1) << 5;
      x0 = *(const float4*)(gB + kn);
      x1 = *(const float4*)(gB + kn + 4);
    }
    int k0 = i << 5;
    short8 ah = *(const short8*)(pa + k0);
    short8 al = *(const short8*)(qa + k0);
    short8 bh0 = *(const short8*)&sB[cb][0][rb0];
    short8 bh1 = *(const short8*)&sB[cb][0][rb1];
    short8 bl0 = *(const short8*)&sB[cb][1][rb0];
    short8 bl1 = *(const short8*)&sB[cb][1][rb1];
    acc0 = __builtin_amdgcn_mfma_f32_16x16x32_bf16(ah, bh0, acc0, 0, 0, 0);
    acc1 = __builtin_amdgcn_mfma_f32_16x16x32_bf16(ah, bh1, acc1, 0, 0, 0);
    acc0 = __builtin_amdgcn_mfma_f32_16x16x32_bf16(ah, bl0, acc0, 0, 0, 0);
    acc1 = __builtin_amdgcn_mfma_f32_16x16x32_bf16(ah, bl1, acc1, 0, 0, 0);
    acc0 = __builtin_amdgcn_mfma_f32_16x16x32_bf16(al, bh0, acc0, 0, 0, 0);
    acc1 = __builtin_amdgcn_mfma_f32_16x16x32_bf16(al, bh1, acc1, 0, 0, 0);
    if (hasNext) {
      float f[8] = {x0.x, x0.y, x0.z, x0.w, x1.x, x1.y, x1.z, x1.w};
      VecU uh, ul;
#pragma unroll
      for (int j = 0; j < 8; ++j) splitbf(f[j], uh.u[j], ul.u[j]);
      *(short8*)&sB[cb ^ 1][0][soff] = uh.s;
      *(short8*)&sB[cb ^ 1][1][soff] = ul.s;
      __syncthreads();
    }
  }

  float* out = Cf + (size_t)blockIdx.z * 32 * N;
  f32x4 av[2] = {acc0, acc1};
#pragma unroll
  for (int u = 0; u < 2; ++u) {
    int n = n0 + wn * 32 + u * 16 + l15;
    if (n >= N) continue;
    f32x4 a = av[u];
#pragma unroll
    for (int reg = 0; reg < 4; ++reg) {
      int m = wm * 16 + (quad << 2) + reg;
      out[(size_t)m * N + n] = a[reg];
    }
  }
}

// ---------------- FC partial reduce + bias + relu + bf16-pair convert ----------------
__global__ void fc_reduce_convert(const float* __restrict__ P, const float* __restrict__ bias,
                                  u16* __restrict__ Ah, u16* __restrict__ Al,
                                  int MN, int N, int zs) {
  int i = blockIdx.x * blockDim.x + threadIdx.x;
  if (i >= MN) return;
  float s = 0.f;
  for (int z = 0; z < zs; ++z) s += P[(size_t)z * MN + i];
  s += bias[i % N];
  if (s < 0.f) s = 0.f;
  u16 hh, ll; splitbf(s, hh, ll);
  Ah[i] = hh; Al[i] = ll;
}

__global__ void fc_reduce_out(const float* __restrict__ P, const float* __restrict__ bias,
                              float* __restrict__ out, int MN, int N, int zs) {
  int i = blockIdx.x * blockDim.x + threadIdx.x;
  if (i >= MN) return;
  float s = 0.f;
  for (int z = 0; z < zs; ++z) s += P[(size_t)z * MN + i];
  out[i] = s + bias[i % N];
}

// ---------------- BN batch stats + fused z-reduce + fused finalize (last block) ----------------
__global__ __launch_bounds__(256) void bn_stats_fused(
    const float* __restrict__ P, float* __restrict__ out, float* __restrict__ st,
    const float* __restrict__ g, const float* __restrict__ bb,
    int M, int C, int rowsPerBlock, int nBlocks, int zs, int writeOut) {
  __shared__ float sh[512];
  __shared__ int isLast;
  size_t MN = (size_t)M * C;
  int t = threadIdx.x;
  int r0 = blockIdx.x * rowsPerBlock;
  int r1 = min(M, r0 + rowsPerBlock);
  if (C >= 256) {
    for (int c = t; c < C; c += 256) {
      float s = 0.f, ss = 0.f;
      for (int r = r0; r < r1; ++r) {
        size_t idx = (size_t)r * C + c;
        float v = P[idx];
        for (int z = 1; z < zs; ++z) v += P[(size_t)z * MN + idx];
        if (writeOut) out[idx] = v;
        s += v; ss += v * v;
      }
      atomicAdd(&st[c], s); atomicAdd(&st[512 + c], ss);
    }
  } else {
    int rpb = 256 / C;
    int c = t % C; int ro = t / C;
    float s = 0.f, ss = 0.f;
    for (int r = r0 + ro; r < r1; r += rpb) {
      size_t idx = (size_t)r * C + c;
      float v = P[idx];
      for (int z = 1; z < zs; ++z) v += P[(size_t)z * MN + idx];
      if (writeOut) out[idx] = v;
      s += v; ss += v * v;
    }
    sh[t] = s; sh[256 + t] = ss;
    __syncthreads();
    if (ro == 0) {
      for (int k = 1; k < rpb; ++k) { s += sh[k * C + c]; ss += sh[256 + k * C + c]; }
      atomicAdd(&st[c], s); atomicAdd(&st[512 + c], ss);
    }
  }
  __syncthreads();
  if (t == 0) {
    __threadfence();
    unsigned old = atomicAdd((unsigned int*)(st + 2048), 1u);
    isLast = (old == (unsigned)(nBlocks - 1)) ? 1 : 0;
  }
  __syncthreads();
  if (isLast) {
    for (int c = t; c < C; c += 256) {
      float s = atomicAdd(&st[c], 0.f);
      float ss = atomicAdd(&st[512 + c], 0.f);
      float mean = s / (float)M;
      float var = ss / (float)M - mean * mean;
      if (var < 0.f) var = 0.f;
      float inv = 1.0f / sqrtf(var + 1e-5f);
      float scv = g[c] * inv;
      st[1024 + c] = scv;
      st[1536 + c] = bb[c] - mean * scv;
    }
  }
}

// -------- permuted 2x2 max pool with fused BN+ReLU on inputs --------
__global__ void pool_kernel(const float* __restrict__ in, const float* __restrict__ stp,
                            float* __restrict__ out,
                            const int* __restrict__ perm, const int* __restrict__ nperm,
                            int B, int H, int C, int total) {
  int i = blockIdx.x * blockDim.x + threadIdx.x;
  if (i >= total) return;
  int oH = H / 2; int oHW = oH * oH; int HW = H * H;
  int c = i % C; int j = (i / C) % oHW; int b = i / (C * oHW);
  float sc = stp[c], sh = stp[512 + c];
  int q = min(max(nperm[j], 0), oHW - 1);
  int qy = q / oH, qx = q % oH;
  float m = 0.f;
#pragma unroll
  for (int dy = 0; dy < 2; ++dy)
#pragma unroll
    for (int dx = 0; dx < 2; ++dx) {
      int p = min(max(perm[(2 * qy + dy) * H + (2 * qx + dx)], 0), HW - 1);
      float v = in[((size_t)b * HW + p) * C + c];
      v = fmaxf(v * sc + sh, 0.f);
      m = fmaxf(m, v);
    }
  out[((size_t)b * oHW + j) * C + c] = m;
}

// target >= 512 four-wave blocks; kPerZ multiple of 32
static inline void pick_split4(int gx, int gy, int Kp, int& zs, int& kPerZ) {
  int gxy = gx * gy;
  zs = 1;
  if (gxy < 512) {
    zs = (512 + gxy - 1) / gxy;
    int maxz = Kp / 32; if (maxz < 1) maxz = 1;
    if (zs > maxz) zs = maxz;
  }
  kPerZ = (((Kp + zs - 1) / zs) + 31) & ~31;
  zs = (Kp + kPerZ - 1) / kPerZ;
}

// FC split: target >= 512 blocks, zs capped at 32
static inline void pick_splitFC(int gy, int K, int& zs, int& kPerZ) {
  zs = (512 + gy - 1) / gy;
  int maxz = K / 32; if (maxz < 1) maxz = 1;
  if (zs > maxz) zs = maxz;
  if (zs > 32) zs = 32;
  kPerZ = (((K + zs - 1) / zs) + 31) & ~31;
  zs = (K + kPerZ - 1) / kPerZ;
}

static inline int ilog2(int v) { int l = 0; while ((1 << l) < v) ++l; return l; }

extern "C" void kernel_launch(void* const* d_in, const int* in_sizes, int n_in,
                              void* d_out, int out_size, void* d_ws, size_t ws_size,
                              hipStream_t stream) {
  const int Ci[13]  = {3, 64, 64, 128, 128, 256, 256, 256, 512, 512, 512, 512, 512};
  const int CoA[13] = {64, 64, 128, 128, 256, 256, 256, 512, 512, 512, 512, 512, 512};
  const int Rr[13]  = {32, 32, 16, 16, 8, 8, 8, 4, 4, 4, 2, 2, 2};
  const int poolAfter[13] = {-1, 0, -1, 1, -1, -1, 2, -1, -1, 3, -1, -1, 4};
  const size_t wOff[13] = {0, 2048, 38912, 112640, 260096, 555008, 1144832, 1734656,
                           2914304, 5273600, 7632896, 9992192, 12351488};
  const int WT_TOTAL = 14710784;
  const int B = 32;
  const int ST = 2304;

  size_t cursor = 0;
  auto alloc = [&](size_t bytes) {
    void* p = (char*)d_ws + cursor;
    cursor += (bytes + 255) & ~(size_t)255;
    return p;
  };
  float* stats = (float*)alloc((size_t)13 * ST * 4);
  u16*   fcPh  = (u16*)alloc((size_t)32 * 4096 * 2);
  u16*   fcPl  = (u16*)alloc((size_t)32 * 4096 * 2);
  float* A0    = (float*)alloc((size_t)2097152 * 4);
  float* A1    = (float*)alloc((size_t)2097152 * 4);
  u16*   WTh   = (u16*)alloc((size_t)WT_TOTAL * 2);
  u16*   WTl   = (u16*)alloc((size_t)WT_TOTAL * 2);
  float* Pbuf  = (float*)alloc((size_t)4194304 * 4);   // 16 MB split-K partials
  u16*   Sh    = (u16*)alloc((size_t)9437184 * 2);     // S: max = L3 (8192x1152)
  u16*   Sl    = (u16*)alloc((size_t)9437184 * 2);
  (void)in_sizes; (void)n_in; (void)out_size;

  hipMemsetAsync(stats, 0, (size_t)13 * ST * 4, stream);

  {
    int total = B * 3 * 1024;
    nchw2nhwc_kernel<<<(total + 255) / 256, 256, 0, stream>>>(
        (const float*)d_in[0], A0, B, 3, 1024);
  }
  wtc_all_v2<<<(PAIR_TOTAL + PAD_TOTAL + 255) / 256, 256, 0, stream>>>(
      (const float*)d_in[2],  (const float*)d_in[7],  (const float*)d_in[12],
      (const float*)d_in[17], (const float*)d_in[22], (const float*)d_in[27],
      (const float*)d_in[32], (const float*)d_in[37], (const float*)d_in[42],
      (const float*)d_in[47], (const float*)d_in[52], (const float*)d_in[57],
      (const float*)d_in[62], WTh, WTl);

  float* cur = A0;
  float* oth = A1;
  int needBN = 0;
  float* stp = nullptr;

  for (int l = 0; l < 13; ++l) {
    int C = Ci[l], N = CoA[l], H = Rr[l];
    int M = B * H * H, K = 9 * C, Kp = (K + 31) & ~31;
    const float* offp = (const float*)d_in[1 + l * 5 + 0];
    const float* gp   = (const float*)d_in[1 + l * 5 + 3];
    const float* bbp  = (const float*)d_in[1 + l * 5 + 4];
    float* st = stats + (size_t)l * ST;

    int gx = M / 64, gy = N / 64;
    int zs, kPerZ;
    pick_split4(gx, gy, Kp, zs, kPerZ);
    float* gemmOut = (zs > 1) ? Pbuf : oth;

    if (l == 0) {
      // C=3: scalar sampler into S, then plain tiled GEMM (gx=512 -> zs=1)
      int work = M * Kp;
      deform_sample_scalar<<<(work + 255) / 256, 256, 0, stream>>>(
          cur, offp, Sh, Sl, 0, M, B, H, H, C, Kp);
      mfma_gemm_tiled<<<dim3(gx, gy, zs), 256, 0, stream>>>(
          Sh, Sl, WTh + wOff[l], WTl + wOff[l], gemmOut, M, N, Kp, kPerZ, zs > 1 ? 1 : 0);
    } else if (gy == 1 && zs == 1) {
      // fusion profitable ONLY at amplification 1 (L1): removes the biggest S round trip
      int lw_ = ilog2(H), lhw_ = 2 * lw_, lc_ = ilog2(C);
      mfma_gemm_fused<<<dim3(gx, gy, zs), 256, 0, stream>>>(
          cur, stp, needBN, offp, WTh + wOff[l], WTl + wOff[l],
          gemmOut, M, N, Kp, kPerZ, 0, H, H, C, lc_, lhw_, lw_);
    } else {
      // standalone sampler (full parallelism, coalesced) + tiled GEMM
      int work = M * 9 * (C >> 3);
      deform_sample_v3<<<(work + 255) / 256, 256, 0, stream>>>(
          cur, stp, needBN, offp, Sh, Sl, 0, M, B, H, H, C, Kp);
      mfma_gemm_tiled<<<dim3(gx, gy, zs), 256, 0, stream>>>(
          Sh, Sl, WTh + wOff[l], WTl + wOff[l], gemmOut, M, N, Kp, kPerZ, zs > 1 ? 1 : 0);
    }

    // adaptive rows/block: keep grid >= ~128 blocks even for tiny M
    int rowsPer = M / 128;
    if (rowsPer < 1) rowsPer = 1;
    if (rowsPer > 64) rowsPer = 64;
    int nB = (M + rowsPer - 1) / rowsPer;
    if (zs > 1)
      bn_stats_fused<<<nB, 256, 0, stream>>>(Pbuf, oth, st, gp, bbp,
                                             M, N, rowsPer, nB, zs, 1);
    else
      bn_stats_fused<<<nB, 256, 0, stream>>>(oth, oth, st, gp, bbp,
                                             M, N, rowsPer, nB, 1, 0);

    if (poolAfter[l] >= 0) {
      int pi = poolAfter[l];
      const int* perm  = (const int*)d_in[66 + pi * 2];
      const int* nperm = (const int*)d_in[66 + pi * 2 + 1];
      int oH = H / 2;
      int total = B * oH * oH * N;
      pool_kernel<<<(total + 255) / 256, 256, 0, stream>>>(oth, st + 1024, cur,
                                                           perm, nperm, B, H, N, total);
      needBN = 0; stp = nullptr;
    } else {
      float* t = cur; cur = oth; oth = t;
      needBN = 1; stp = st + 1024;
    }
  }

  // FC head: cur = [32, 512] fp32 (BN+ReLU applied by final pool)
  const float* fw1 = (const float*)d_in[76]; const float* fb1 = (const float*)d_in[77];
  const float* fw2 = (const float*)d_in[78]; const float* fb2 = (const float*)d_in[79];
  const float* fw3 = (const float*)d_in[80]; const float* fb3 = (const float*)d_in[81];
  {
    int zs, kPerZ;
    act_convert<<<(32 * 512 + 255) / 256, 256, 0, stream>>>(cur, fcPh, fcPl, 32 * 512);
    // FC1: 32x4096x512
    pick_splitFC(64, 512, zs, kPerZ);
    mfma_gemm_fc4<<<dim3(1, 64, zs), 256, 0, stream>>>(fcPh, fcPl, fw1, Pbuf,
                                                       4096, 512, kPerZ);
    fc_reduce_convert<<<(32 * 4096 + 255) / 256, 256, 0, stream>>>(
        Pbuf, fb1, fcPh, fcPl, 32 * 4096, 4096, zs);
    // FC2: 32x4096x4096
    pick_splitFC(64, 4096, zs, kPerZ);
    mfma_gemm_fc4<<<dim3(1, 64, zs), 256, 0, stream>>>(fcPh, fcPl, fw2, Pbuf,
                                                       4096, 4096, kPerZ);
    fc_reduce_convert<<<(32 * 4096 + 255) / 256, 256, 0, stream>>>(
        Pbuf, fb2, fcPh, fcPl, 32 * 4096, 4096, zs);
    // FC3: 32x100x4096
    pick_splitFC(2, 4096, zs, kPerZ);
    mfma_gemm_fc4<<<dim3(1, 2, zs), 256, 0, stream>>>(fcPh, fcPl, fw3, Pbuf,
                                                      100, 4096, kPerZ);
    fc_reduce_out<<<(3200 + 255) / 256, 256, 0, stream>>>(
        Pbuf, fb3, (float*)d_out, 3200, 100, zs);
  }
}

// Round 12
// 892.503 us; speedup vs baseline: 1.0141x; 1.0141x over previous
//
#include <hip/hip_runtime.h>
#include <hip/hip_bf16.h>

typedef __hip_bfloat16 bf16;
typedef __attribute__((ext_vector_type(8))) short short8;
typedef __attribute__((ext_vector_type(4))) float f32x4;
typedef unsigned short u16;
#define BF2F(x) __bfloat162float(x)

__device__ __forceinline__ u16 f2bfbits(float v) {
  bf16 h = __float2bfloat16(v);
  return *(u16*)&h;
}
__device__ __forceinline__ float bfbits2f(u16 u) {
  bf16 h; *(u16*)&h = u;
  return BF2F(h);
}
__device__ __forceinline__ void splitbf(float v, u16& hi, u16& lo) {
  hi = f2bfbits(v);
  lo = f2bfbits(v - bfbits2f(hi));
}

union VecU {
  u16 u[8];
  short8 s;
};

// ---------------- NCHW(f32) -> NHWC(f32) ----------------
__global__ void nchw2nhwc_kernel(const float* __restrict__ in, float* __restrict__ out,
                                 int B, int C, int HW) {
  int i = blockIdx.x * blockDim.x + threadIdx.x;
  int total = B * C * HW;
  if (i >= total) return;
  int c = i % C; int p = (i / C) % HW; int b = i / (C * HW);
  out[i] = in[((size_t)b * C + c) * HW + p];
}

// ------- ALL conv weights -> bf16 hi/lo [co][k2*C+ci], one launch, coalesced -------
template<int C, int Kp>
__device__ __forceinline__ void wtc_pair(const float* __restrict__ w, u16* __restrict__ Wh,
                                         u16* __restrict__ Wl, int rel) {
  int co = rel / C, ci = rel % C;
  const float* src = w + ((size_t)co * C + ci) * 9;
  float v[9];
#pragma unroll
  for (int k2 = 0; k2 < 9; ++k2) v[k2] = src[k2];
  size_t ob = (size_t)co * Kp + ci;
#pragma unroll
  for (int k2 = 0; k2 < 9; ++k2) {
    u16 hh, ll; splitbf(v[k2], hh, ll);
    Wh[ob + (size_t)k2 * C] = hh;
    Wl[ob + (size_t)k2 * C] = ll;
  }
}

#define PAIR_TOTAL 1634496
#define PAD_TOTAL 320   // layer-0: 64 rows x (32-27) pad elems

__global__ void wtc_all_v2(
    const float* w0, const float* w1, const float* w2, const float* w3,
    const float* w4, const float* w5, const float* w6, const float* w7,
    const float* w8, const float* w9, const float* w10, const float* w11,
    const float* w12, u16* __restrict__ Wh, u16* __restrict__ Wl) {
  int i = blockIdx.x * blockDim.x + threadIdx.x;
  if (i >= PAIR_TOTAL + PAD_TOTAL) return;
  if (i >= PAIR_TOTAL) {  // zero layer-0 pad: Wh[co*32 + k], k in [27,32)
    int t = i - PAIR_TOTAL;
    int co = t / 5, k = 27 + t % 5;
    int o = co * 32 + k;
    Wh[o] = 0; Wl[o] = 0;
    return;
  }
  if      (i < 192)     wtc_pair<3, 32>(w0, Wh + 0, Wl + 0, i);
  else if (i < 4288)    wtc_pair<64, 576>(w1, Wh + 2048, Wl + 2048, i - 192);
  else if (i < 12480)   wtc_pair<64, 576>(w2, Wh + 38912, Wl + 38912, i - 4288);
  else if (i < 28864)   wtc_pair<128, 1152>(w3, Wh + 112640, Wl + 112640, i - 12480);
  else if (i < 61632)   wtc_pair<128, 1152>(w4, Wh + 260096, Wl + 260096, i - 28864);
  else if (i < 127168)  wtc_pair<256, 2304>(w5, Wh + 555008, Wl + 555008, i - 61632);
  else if (i < 192704)  wtc_pair<256, 2304>(w6, Wh + 1144832, Wl + 1144832, i - 127168);
  else if (i < 323776)  wtc_pair<256, 2304>(w7, Wh + 1734656, Wl + 1734656, i - 192704);
  else if (i < 585920)  wtc_pair<512, 4608>(w8, Wh + 2914304, Wl + 2914304, i - 323776);
  else if (i < 848064)  wtc_pair<512, 4608>(w9, Wh + 5273600, Wl + 5273600, i - 585920);
  else if (i < 1110208) wtc_pair<512, 4608>(w10, Wh + 7632896, Wl + 7632896, i - 848064);
  else if (i < 1372352) wtc_pair<512, 4608>(w11, Wh + 9992192, Wl + 9992192, i - 1110208);
  else                  wtc_pair<512, 4608>(w12, Wh + 12351488, Wl + 12351488, i - 1372352);
}

// ------- fp32 activations -> bf16 hi/lo pair -------
__global__ void act_convert(const float* __restrict__ x,
                            u16* __restrict__ Ah, u16* __restrict__ Al, int total) {
  int i = blockIdx.x * blockDim.x + threadIdx.x;
  if (i >= total) return;
  u16 hh, ll; splitbf(x[i], hh, ll);
  Ah[i] = hh; Al[i] = ll;
}

// ------- deformable sampling: thread = (pixel, k2, 8-channel chunk) -------
__global__ __launch_bounds__(256) void deform_sample_v3(
    const float* __restrict__ act, const float* __restrict__ stp, int bnmode,
    const float* __restrict__ off, u16* __restrict__ Sh, u16* __restrict__ Sl,
    int m0, int Mc, int B, int H, int W, int C, int Kp) {
  int i = blockIdx.x * blockDim.x + threadIdx.x;
  int c8n = C >> 3;
  int total = Mc * 9 * c8n;
  if (i >= total) return;
  int c8 = i % c8n;
  int t = i / c8n;
  int k2 = t % 9;
  int ml = t / 9;
  int m = m0 + ml;
  int HW = H * W;
  int b = m / HW; int p = m - b * HW; int y = p / W; int x = p - y * W;
  size_t ob = (size_t)b * 18 * HW + p;
  float dy = off[ob + (size_t)(2 * k2) * HW];
  float dx = off[ob + (size_t)(2 * k2 + 1) * HW];
  float py = (float)(y + k2 / 3 - 1) + dy;
  float px = (float)(x + k2 % 3 - 1) + dx;
  float y0f = floorf(py), x0f = floorf(px);
  float wy = py - y0f, wx = px - x0f;
  int iy0 = (int)y0f, ix0 = (int)x0f;
  int iy1 = iy0 + 1, ix1 = ix0 + 1;
  float w00 = (1.f - wy) * (1.f - wx), w01 = (1.f - wy) * wx;
  float w10 = wy * (1.f - wx), w11 = wy * wx;
  if (iy0 < 0 || iy0 >= H) { w00 = 0.f; w01 = 0.f; }
  if (iy1 < 0 || iy1 >= H) { w10 = 0.f; w11 = 0.f; }
  if (ix0 < 0 || ix0 >= W) { w00 = 0.f; w10 = 0.f; }
  if (ix1 < 0 || ix1 >= W) { w01 = 0.f; w11 = 0.f; }
  int cy0 = min(max(iy0, 0), H - 1), cy1 = min(max(iy1, 0), H - 1);
  int cx0 = min(max(ix0, 0), W - 1), cx1 = min(max(ix1, 0), W - 1);
  int c = c8 << 3;
  size_t rowb = (size_t)b * HW;
  const float* p00 = act + (rowb + cy0 * W + cx0) * C + c;
  const float* p01 = act + (rowb + cy0 * W + cx1) * C + c;
  const float* p10 = act + (rowb + cy1 * W + cx0) * C + c;
  const float* p11 = act + (rowb + cy1 * W + cx1) * C + c;
  float4 a00 = *(const float4*)p00, b00 = *(const float4*)(p00 + 4);
  float4 a01 = *(const float4*)p01, b01 = *(const float4*)(p01 + 4);
  float4 a10 = *(const float4*)p10, b10 = *(const float4*)(p10 + 4);
  float4 a11 = *(const float4*)p11, b11 = *(const float4*)(p11 + 4);
  float v00[8] = {a00.x, a00.y, a00.z, a00.w, b00.x, b00.y, b00.z, b00.w};
  float v01[8] = {a01.x, a01.y, a01.z, a01.w, b01.x, b01.y, b01.z, b01.w};
  float v10[8] = {a10.x, a10.y, a10.z, a10.w, b10.x, b10.y, b10.z, b10.w};
  float v11[8] = {a11.x, a11.y, a11.z, a11.w, b11.x, b11.y, b11.z, b11.w};
  if (bnmode) {
    float4 s0 = *(const float4*)(stp + c), s1 = *(const float4*)(stp + c + 4);
    float4 h0 = *(const float4*)(stp + 512 + c), h1 = *(const float4*)(stp + 512 + c + 4);
    float sc[8] = {s0.x, s0.y, s0.z, s0.w, s1.x, s1.y, s1.z, s1.w};
    float sh[8] = {h0.x, h0.y, h0.z, h0.w, h1.x, h1.y, h1.z, h1.w};
#pragma unroll
    for (int j = 0; j < 8; ++j) {
      v00[j] = fmaxf(v00[j] * sc[j] + sh[j], 0.f);
      v01[j] = fmaxf(v01[j] * sc[j] + sh[j], 0.f);
      v10[j] = fmaxf(v10[j] * sc[j] + sh[j], 0.f);
      v11[j] = fmaxf(v11[j] * sc[j] + sh[j], 0.f);
    }
  }
  VecU uh, ul;
#pragma unroll
  for (int j = 0; j < 8; ++j) {
    float r = w00 * v00[j] + w01 * v01[j] + w10 * v10[j] + w11 * v11[j];
    splitbf(r, uh.u[j], ul.u[j]);
  }
  size_t base = (size_t)ml * Kp + (size_t)k2 * C + c;
  *(short8*)(Sh + base) = uh.s;
  *(short8*)(Sl + base) = ul.s;
}

// ------- scalar variant for layer 0 (C=3, K=27, Kp=32; covers zero padding) -------
__global__ __launch_bounds__(256) void deform_sample_scalar(
    const float* __restrict__ act, const float* __restrict__ off,
    u16* __restrict__ Sh, u16* __restrict__ Sl,
    int m0, int Mc, int B, int H, int W, int C, int Kp) {
  int i = blockIdx.x * blockDim.x + threadIdx.x;
  int total = Mc * Kp;
  if (i >= total) return;
  int kp = i % Kp;
  int ml = i / Kp;
  float val = 0.f;
  int K = 9 * C;
  if (kp < K) {
    int c = kp % C; int k2 = kp / C;
    int m = m0 + ml;
    int HW = H * W;
    int b = m / HW; int p = m - b * HW; int y = p / W; int x = p - y * W;
    size_t ob = (size_t)b * 18 * HW + p;
    float dy = off[ob + (size_t)(2 * k2) * HW];
    float dx = off[ob + (size_t)(2 * k2 + 1) * HW];
    float py = (float)(y + k2 / 3 - 1) + dy;
    float px = (float)(x + k2 % 3 - 1) + dx;
    float y0f = floorf(py), x0f = floorf(px);
    float wy = py - y0f, wx = px - x0f;
    int iy0 = (int)y0f, ix0 = (int)x0f;
    int iy1 = iy0 + 1, ix1 = ix0 + 1;
    float w00 = (1.f - wy) * (1.f - wx), w01 = (1.f - wy) * wx;
    float w10 = wy * (1.f - wx), w11 = wy * wx;
    if (iy0 < 0 || iy0 >= H) { w00 = 0.f; w01 = 0.f; }
    if (iy1 < 0 || iy1 >= H) { w10 = 0.f; w11 = 0.f; }
    if (ix0 < 0 || ix0 >= W) { w00 = 0.f; w10 = 0.f; }
    if (ix1 < 0 || ix1 >= W) { w01 = 0.f; w11 = 0.f; }
    int cy0 = min(max(iy0, 0), H - 1), cy1 = min(max(iy1, 0), H - 1);
    int cx0 = min(max(ix0, 0), W - 1), cx1 = min(max(ix1, 0), W - 1);
    size_t rowb = (size_t)b * HW;
    float v00 = act[(rowb + cy0 * W + cx0) * C + c];
    float v01 = act[(rowb + cy0 * W + cx1) * C + c];
    float v10 = act[(rowb + cy1 * W + cx0) * C + c];
    float v11 = act[(rowb + cy1 * W + cx1) * C + c];
    val = w00 * v00 + w01 * v01 + w10 * v10 + w11 * v11;
  }
  u16 hh, ll; splitbf(val, hh, ll);
  size_t base = (size_t)ml * Kp + kp;
  Sh[base] = hh; Sl[base] = ll;
}

// ---------------- 4-wave tiled MFMA GEMM (bf16x3), 64x64 tile, dbuf LDS ----------------
#define LDA 40  // u16 units per LDS row (32 data + 8 pad -> 2-way bank alias only)

__global__ __launch_bounds__(256) void mfma_gemm_tiled(
    const u16* __restrict__ Ah, const u16* __restrict__ Al,
    const u16* __restrict__ Bh, const u16* __restrict__ Bl,
    float* __restrict__ Cf, int M, int N, int Kp, int kPerZ, int splitMode) {
  __shared__ __align__(16) u16 lds[2 * 4 * 64 * LDA];
  const int TS = 64 * LDA;
  const int BS = 4 * TS;
  int tid = threadIdx.x;
  int lane = tid & 63, wave = tid >> 6;
  int l15 = lane & 15, quad = lane >> 4;
  int wr = wave >> 1, wc = wave & 1;
  int m0 = blockIdx.x * 64, n0 = blockIdx.y * 64;
  int kStart = blockIdx.z * kPerZ;
  int kEnd = min(Kp, kStart + kPerZ);
  int nSteps = (kEnd - kStart) >> 5;

  int sr = tid >> 2, sc = (tid & 3) << 3;
  const u16* gAh = Ah + (size_t)(m0 + sr) * Kp + kStart + sc;
  const u16* gAl = Al + (size_t)(m0 + sr) * Kp + kStart + sc;
  const u16* gBh = Bh + (size_t)(n0 + sr) * Kp + kStart + sc;
  const u16* gBl = Bl + (size_t)(n0 + sr) * Kp + kStart + sc;
  int soff = sr * LDA + sc;

  f32x4 z4 = {0.f, 0.f, 0.f, 0.f};
  f32x4 acc00 = z4, acc01 = z4, acc10 = z4, acc11 = z4;

  {
    short8 a = *(const short8*)gAh;
    short8 b = *(const short8*)gAl;
    short8 c = *(const short8*)gBh;
    short8 d = *(const short8*)gBl;
    *(short8*)&lds[0 * TS + soff] = a;
    *(short8*)&lds[1 * TS + soff] = b;
    *(short8*)&lds[2 * TS + soff] = c;
    *(short8*)&lds[3 * TS + soff] = d;
  }
  __syncthreads();

  int raoff = (wr * 32 + l15) * LDA + quad * 8;
  int rboff = (wc * 32 + l15) * LDA + quad * 8;

  for (int i = 0; i < nSteps; ++i) {
    int cb = (i & 1) * BS;
    bool hasNext = (i + 1 < nSteps);
    short8 nA, nB, nC, nD;
    if (hasNext) {
      int kn = (i + 1) << 5;
      nA = *(const short8*)(gAh + kn);
      nB = *(const short8*)(gAl + kn);
      nC = *(const short8*)(gBh + kn);
      nD = *(const short8*)(gBl + kn);
    }
    short8 ah0 = *(const short8*)&lds[cb + 0 * TS + raoff];
    short8 ah1 = *(const short8*)&lds[cb + 0 * TS + raoff + 16 * LDA];
    short8 al0 = *(const short8*)&lds[cb + 1 * TS + raoff];
    short8 al1 = *(const short8*)&lds[cb + 1 * TS + raoff + 16 * LDA];
    short8 bh0 = *(const short8*)&lds[cb + 2 * TS + rboff];
    short8 bh1 = *(const short8*)&lds[cb + 2 * TS + rboff + 16 * LDA];
    short8 bl0 = *(const short8*)&lds[cb + 3 * TS + rboff];
    short8 bl1 = *(const short8*)&lds[cb + 3 * TS + rboff + 16 * LDA];
    acc00 = __builtin_amdgcn_mfma_f32_16x16x32_bf16(ah0, bh0, acc00, 0, 0, 0);
    acc01 = __builtin_amdgcn_mfma_f32_16x16x32_bf16(ah0, bh1, acc01, 0, 0, 0);
    acc10 = __builtin_amdgcn_mfma_f32_16x16x32_bf16(ah1, bh0, acc10, 0, 0, 0);
    acc11 = __builtin_amdgcn_mfma_f32_16x16x32_bf16(ah1, bh1, acc11, 0, 0, 0);
    acc00 = __builtin_amdgcn_mfma_f32_16x16x32_bf16(ah0, bl0, acc00, 0, 0, 0);
    acc01 = __builtin_amdgcn_mfma_f32_16x16x32_bf16(ah0, bl1, acc01, 0, 0, 0);
    acc10 = __builtin_amdgcn_mfma_f32_16x16x32_bf16(ah1, bl0, acc10, 0, 0, 0);
    acc11 = __builtin_amdgcn_mfma_f32_16x16x32_bf16(ah1, bl1, acc11, 0, 0, 0);
    acc00 = __builtin_amdgcn_mfma_f32_16x16x32_bf16(al0, bh0, acc00, 0, 0, 0);
    acc01 = __builtin_amdgcn_mfma_f32_16x16x32_bf16(al0, bh1, acc01, 0, 0, 0);
    acc10 = __builtin_amdgcn_mfma_f32_16x16x32_bf16(al1, bh0, acc10, 0, 0, 0);
    acc11 = __builtin_amdgcn_mfma_f32_16x16x32_bf16(al1, bh1, acc11, 0, 0, 0);
    if (hasNext) {
      int ob = cb ^ BS;
      *(short8*)&lds[ob + 0 * TS + soff] = nA;
      *(short8*)&lds[ob + 1 * TS + soff] = nB;
      *(short8*)&lds[ob + 2 * TS + soff] = nC;
      *(short8*)&lds[ob + 3 * TS + soff] = nD;
      __syncthreads();
    }
  }

  float* out = Cf + (splitMode ? (size_t)blockIdx.z * M * N : (size_t)0);
  f32x4 av[2][2] = {{acc00, acc01}, {acc10, acc11}};
#pragma unroll
  for (int t = 0; t < 2; ++t) {
    int mB = m0 + wr * 32 + t * 16 + (quad << 2);
#pragma unroll
    for (int u = 0; u < 2; ++u) {
      int n = n0 + wc * 32 + u * 16 + l15;
      f32x4 a = av[t][u];
#pragma unroll
      for (int reg = 0; reg < 4; ++reg) {
        int m = mB + reg;
        out[(size_t)m * N + n] = a[reg];
      }
    }
  }
}

// ---------------- FUSED deformable-sample + GEMM (gy==1 layers; split-K capable) --------
// A-tile is sampled on the fly (bilinear + optional BN+ReLU on prev act), no S buffer.
// Sampling work partitions exactly across z-blocks (k-ranges are channel/tap partitions).
// Requires: C power of 2 (>=64), Kp = 9*C, M,N multiples of 64, H=W power of 2.
__global__ __launch_bounds__(256) void mfma_gemm_fused(
    const float* __restrict__ act, const float* __restrict__ stp, int bnmode,
    const float* __restrict__ off,
    const u16* __restrict__ Bh, const u16* __restrict__ Bl,
    float* __restrict__ Cf, int M, int N, int Kp, int kPerZ, int splitMode,
    int H, int W, int C, int lc, int lhw, int lw) {
  __shared__ __align__(16) u16 lds[2 * 4 * 64 * LDA];
  const int TS = 64 * LDA;
  const int BS = 4 * TS;
  int tid = threadIdx.x;
  int lane = tid & 63, wave = tid >> 6;
  int l15 = lane & 15, quad = lane >> 4;
  int wr = wave >> 1, wc = wave & 1;
  int m0 = blockIdx.x * 64, n0 = blockIdx.y * 64;
  int kStart = blockIdx.z * kPerZ;
  int kEnd = min(Kp, kStart + kPerZ);
  int nSteps = (kEnd - kStart) >> 5;

  int sr = tid >> 2, sc = (tid & 3) << 3;
  int HWv = H * W;
  int m = m0 + sr;
  int b = m >> lhw; int p = m & (HWv - 1); int y = p >> lw; int x = p & (W - 1);
  size_t obase = (size_t)b * 18 * HWv + p;
  size_t rowb = (size_t)b * HWv;
  const u16* gBh = Bh + (size_t)(n0 + sr) * Kp + kStart + sc;
  const u16* gBl = Bl + (size_t)(n0 + sr) * Kp + kStart + sc;
  int soff = sr * LDA + sc;

  f32x4 z4 = {0.f, 0.f, 0.f, 0.f};
  f32x4 acc00 = z4, acc01 = z4, acc10 = z4, acc11 = z4;

  auto SAMPLE = [&](int kk, short8& uh8, short8& ul8) {
    int k2 = kk >> lc;
    int ci = kk & (C - 1);
    float dy = off[obase + (size_t)(2 * k2) * HWv];
    float dx = off[obase + (size_t)(2 * k2 + 1) * HWv];
    float py = (float)(y + k2 / 3 - 1) + dy;
    float px = (float)(x + k2 % 3 - 1) + dx;
    float y0f = floorf(py), x0f = floorf(px);
    float wy = py - y0f, wx = px - x0f;
    int iy0 = (int)y0f, ix0 = (int)x0f;
    int iy1 = iy0 + 1, ix1 = ix0 + 1;
    float w00 = (1.f - wy) * (1.f - wx), w01 = (1.f - wy) * wx;
    float w10 = wy * (1.f - wx), w11 = wy * wx;
    if (iy0 < 0 || iy0 >= H) { w00 = 0.f; w01 = 0.f; }
    if (iy1 < 0 || iy1 >= H) { w10 = 0.f; w11 = 0.f; }
    if (ix0 < 0 || ix0 >= W) { w00 = 0.f; w10 = 0.f; }
    if (ix1 < 0 || ix1 >= W) { w01 = 0.f; w11 = 0.f; }
    int cy0 = min(max(iy0, 0), H - 1), cy1 = min(max(iy1, 0), H - 1);
    int cx0 = min(max(ix0, 0), W - 1), cx1 = min(max(ix1, 0), W - 1);
    const float* p00 = act + (rowb + cy0 * W + cx0) * C + ci;
    const float* p01 = act + (rowb + cy0 * W + cx1) * C + ci;
    const float* p10 = act + (rowb + cy1 * W + cx0) * C + ci;
    const float* p11 = act + (rowb + cy1 * W + cx1) * C + ci;
    float4 a00 = *(const float4*)p00, b00 = *(const float4*)(p00 + 4);
    float4 a01 = *(const float4*)p01, b01 = *(const float4*)(p01 + 4);
    float4 a10 = *(const float4*)p10, b10 = *(const float4*)(p10 + 4);
    float4 a11 = *(const float4*)p11, b11 = *(const float4*)(p11 + 4);
    float v00[8] = {a00.x, a00.y, a00.z, a00.w, b00.x, b00.y, b00.z, b00.w};
    float v01[8] = {a01.x, a01.y, a01.z, a01.w, b01.x, b01.y, b01.z, b01.w};
    float v10[8] = {a10.x, a10.y, a10.z, a10.w, b10.x, b10.y, b10.z, b10.w};
    float v11[8] = {a11.x, a11.y, a11.z, a11.w, b11.x, b11.y, b11.z, b11.w};
    if (bnmode) {
      float4 s0 = *(const float4*)(stp + ci), s1 = *(const float4*)(stp + ci + 4);
      float4 h0 = *(const float4*)(stp + 512 + ci), h1 = *(const float4*)(stp + 512 + ci + 4);
      float scv[8] = {s0.x, s0.y, s0.z, s0.w, s1.x, s1.y, s1.z, s1.w};
      float shv[8] = {h0.x, h0.y, h0.z, h0.w, h1.x, h1.y, h1.z, h1.w};
#pragma unroll
      for (int j = 0; j < 8; ++j) {
        v00[j] = fmaxf(v00[j] * scv[j] + shv[j], 0.f);
        v01[j] = fmaxf(v01[j] * scv[j] + shv[j], 0.f);
        v10[j] = fmaxf(v10[j] * scv[j] + shv[j], 0.f);
        v11[j] = fmaxf(v11[j] * scv[j] + shv[j], 0.f);
      }
    }
    VecU uh, ul;
#pragma unroll
    for (int j = 0; j < 8; ++j) {
      float r = w00 * v00[j] + w01 * v01[j] + w10 * v10[j] + w11 * v11[j];
      splitbf(r, uh.u[j], ul.u[j]);
    }
    uh8 = uh.s; ul8 = ul.s;
  };

  {  // prologue
    short8 sa, sb;
    SAMPLE(kStart + sc, sa, sb);
    short8 c = *(const short8*)gBh;
    short8 d = *(const short8*)gBl;
    *(short8*)&lds[0 * TS + soff] = sa;
    *(short8*)&lds[1 * TS + soff] = sb;
    *(short8*)&lds[2 * TS + soff] = c;
    *(short8*)&lds[3 * TS + soff] = d;
  }
  __syncthreads();

  int raoff = (wr * 32 + l15) * LDA + quad * 8;
  int rboff = (wc * 32 + l15) * LDA + quad * 8;

  for (int i = 0; i < nSteps; ++i) {
    int cb = (i & 1) * BS;
    bool hasNext = (i + 1 < nSteps);
    short8 nA, nB, nC, nD;
    if (hasNext) {
      int kn = (i + 1) << 5;
      SAMPLE(kStart + kn + sc, nA, nB);
      nC = *(const short8*)(gBh + kn);
      nD = *(const short8*)(gBl + kn);
    }
    short8 ah0 = *(const short8*)&lds[cb + 0 * TS + raoff];
    short8 ah1 = *(const short8*)&lds[cb + 0 * TS + raoff + 16 * LDA];
    short8 al0 = *(const short8*)&lds[cb + 1 * TS + raoff];
    short8 al1 = *(const short8*)&lds[cb + 1 * TS + raoff + 16 * LDA];
    short8 bh0 = *(const short8*)&lds[cb + 2 * TS + rboff];
    short8 bh1 = *(const short8*)&lds[cb + 2 * TS + rboff + 16 * LDA];
    short8 bl0 = *(const short8*)&lds[cb + 3 * TS + rboff];
    short8 bl1 = *(const short8*)&lds[cb + 3 * TS + rboff + 16 * LDA];
    acc00 = __builtin_amdgcn_mfma_f32_16x16x32_bf16(ah0, bh0, acc00, 0, 0, 0);
    acc01 = __builtin_amdgcn_mfma_f32_16x16x32_bf16(ah0, bh1, acc01, 0, 0, 0);
    acc10 = __builtin_amdgcn_mfma_f32_16x16x32_bf16(ah1, bh0, acc10, 0, 0, 0);
    acc11 = __builtin_amdgcn_mfma_f32_16x16x32_bf16(ah1, bh1, acc11, 0, 0, 0);
    acc00 = __builtin_amdgcn_mfma_f32_16x16x32_bf16(ah0, bl0, acc00, 0, 0, 0);
    acc01 = __builtin_amdgcn_mfma_f32_16x16x32_bf16(ah0, bl1, acc01, 0, 0, 0);
    acc10 = __builtin_amdgcn_mfma_f32_16x16x32_bf16(ah1, bl0, acc10, 0, 0, 0);
    acc11 = __builtin_amdgcn_mfma_f32_16x16x32_bf16(ah1, bl1, acc11, 0, 0, 0);
    acc00 = __builtin_amdgcn_mfma_f32_16x16x32_bf16(al0, bh0, acc00, 0, 0, 0);
    acc01 = __builtin_amdgcn_mfma_f32_16x16x32_bf16(al0, bh1, acc01, 0, 0, 0);
    acc10 = __builtin_amdgcn_mfma_f32_16x16x32_bf16(al1, bh0, acc10, 0, 0, 0);
    acc11 = __builtin_amdgcn_mfma_f32_16x16x32_bf16(al1, bh1, acc11, 0, 0, 0);
    if (hasNext) {
      int ob = cb ^ BS;
      *(short8*)&lds[ob + 0 * TS + soff] = nA;
      *(short8*)&lds[ob + 1 * TS + soff] = nB;
      *(short8*)&lds[ob + 2 * TS + soff] = nC;
      *(short8*)&lds[ob + 3 * TS + soff] = nD;
      __syncthreads();
    }
  }

  float* out = Cf + (splitMode ? (size_t)blockIdx.z * M * N : (size_t)0);
  f32x4 av[2][2] = {{acc00, acc01}, {acc10, acc11}};
#pragma unroll
  for (int t = 0; t < 2; ++t) {
    int mB = m0 + wr * 32 + t * 16 + (quad << 2);
#pragma unroll
    for (int u = 0; u < 2; ++u) {
      int n = n0 + wc * 32 + u * 16 + l15;
      f32x4 a = av[t][u];
#pragma unroll
      for (int reg = 0; reg < 4; ++reg) {
        int mm = mB + reg;
        out[(size_t)mm * N + n] = a[reg];
      }
    }
  }
}

// ---------------- FC: 4-wave, M=32 fixed, B fp32 staged->bf16 pair in LDS ----------------
#define LDAF 40

__global__ __launch_bounds__(256) void mfma_gemm_fc4(
    const u16* __restrict__ Ah, const u16* __restrict__ Al,
    const float* __restrict__ Bw, float* __restrict__ Cf,
    int N, int K, int kPerZ) {
  __shared__ __align__(16) u16 sB[2][2][64 * LDAF];
  int tid = threadIdx.x;
  int lane = tid & 63, wave = tid >> 6;
  int l15 = lane & 15, quad = lane >> 4;
  int wm = wave >> 1, wn = wave & 1;
  int n0 = blockIdx.y * 64;
  int kStart = blockIdx.z * kPerZ;
  int kEnd = min(K, kStart + kPerZ);
  int nSteps = (kEnd - kStart) >> 5;

  int sr = tid >> 2, sc = (tid & 3) << 3;
  int gn = n0 + sr; if (gn >= N) gn = 0;
  const float* gB = Bw + (size_t)gn * K + kStart + sc;
  int soff = sr * LDAF + sc;

  const u16* pa = Ah + (size_t)(wm * 16 + l15) * K + kStart + (quad << 3);
  const u16* qa = Al + (size_t)(wm * 16 + l15) * K + kStart + (quad << 3);

  f32x4 z4 = {0.f, 0.f, 0.f, 0.f};
  f32x4 acc0 = z4, acc1 = z4;

  {
    float4 x0 = *(const float4*)gB;
    float4 x1 = *(const float4*)(gB + 4);
    float f[8] = {x0.x, x0.y, x0.z, x0.w, x1.x, x1.y, x1.z, x1.w};
    VecU uh, ul;
#pragma unroll
    for (int j = 0; j < 8; ++j) splitbf(f[j], uh.u[j], ul.u[j]);
    *(short8*)&sB[0][0][soff] = uh.s;
    *(short8*)&sB[0][1][soff] = ul.s;
  }
  __syncthreads();

  int rb0 = (wn * 32 + l15) * LDAF + (quad << 3);
  int rb1 = (wn * 32 + 16 + l15) * LDAF + (quad << 3);

  for (int i = 0; i < nSteps; ++i) {
    int cb = i & 1;
    bool hasNext = (i + 1 < nSteps);
    float4 x0, x1;
    if (hasNext) {
      int kn = (i + 1) << 5;
      x0 = *(const float4*)(gB + kn);
      x1 = *(const float4*)(gB + kn + 4);
    }
    int k0 = i << 5;
    short8 ah = *(const short8*)(pa + k0);
    short8 al = *(const short8*)(qa + k0);
    short8 bh0 = *(const short8*)&sB[cb][0][rb0];
    short8 bh1 = *(const short8*)&sB[cb][0][rb1];
    short8 bl0 = *(const short8*)&sB[cb][1][rb0];
    short8 bl1 = *(const short8*)&sB[cb][1][rb1];
    acc0 = __builtin_amdgcn_mfma_f32_16x16x32_bf16(ah, bh0, acc0, 0, 0, 0);
    acc1 = __builtin_amdgcn_mfma_f32_16x16x32_bf16(ah, bh1, acc1, 0, 0, 0);
    acc0 = __builtin_amdgcn_mfma_f32_16x16x32_bf16(ah, bl0, acc0, 0, 0, 0);
    acc1 = __builtin_amdgcn_mfma_f32_16x16x32_bf16(ah, bl1, acc1, 0, 0, 0);
    acc0 = __builtin_amdgcn_mfma_f32_16x16x32_bf16(al, bh0, acc0, 0, 0, 0);
    acc1 = __builtin_amdgcn_mfma_f32_16x16x32_bf16(al, bh1, acc1, 0, 0, 0);
    if (hasNext) {
      float f[8] = {x0.x, x0.y, x0.z, x0.w, x1.x, x1.y, x1.z, x1.w};
      VecU uh, ul;
#pragma unroll
      for (int j = 0; j < 8; ++j) splitbf(f[j], uh.u[j], ul.u[j]);
      *(short8*)&sB[cb ^ 1][0][soff] = uh.s;
      *(short8*)&sB[cb ^ 1][1][soff] = ul.s;
      __syncthreads();
    }
  }

  float* out = Cf + (size_t)blockIdx.z * 32 * N;
  f32x4 av[2] = {acc0, acc1};
#pragma unroll
  for (int u = 0; u < 2; ++u) {
    int n = n0 + wn * 32 + u * 16 + l15;
    if (n >= N) continue;
    f32x4 a = av[u];
#pragma unroll
    for (int reg = 0; reg < 4; ++reg) {
      int m = wm * 16 + (quad << 2) + reg;
      out[(size_t)m * N + n] = a[reg];
    }
  }
}

// ---------------- FC partial reduce + bias + relu + bf16-pair convert ----------------
__global__ void fc_reduce_convert(const float* __restrict__ P, const float* __restrict__ bias,
                                  u16* __restrict__ Ah, u16* __restrict__ Al,
                                  int MN, int N, int zs) {
  int i = blockIdx.x * blockDim.x + threadIdx.x;
  if (i >= MN) return;
  float s = 0.f;
  for (int z = 0; z < zs; ++z) s += P[(size_t)z * MN + i];
  s += bias[i % N];
  if (s < 0.f) s = 0.f;
  u16 hh, ll; splitbf(s, hh, ll);
  Ah[i] = hh; Al[i] = ll;
}

__global__ void fc_reduce_out(const float* __restrict__ P, const float* __restrict__ bias,
                              float* __restrict__ out, int MN, int N, int zs) {
  int i = blockIdx.x * blockDim.x + threadIdx.x;
  if (i >= MN) return;
  float s = 0.f;
  for (int z = 0; z < zs; ++z) s += P[(size_t)z * MN + i];
  out[i] = s + bias[i % N];
}

// ---------------- BN batch stats + fused z-reduce + fused finalize (last block) ----------------
__global__ __launch_bounds__(256) void bn_stats_fused(
    const float* __restrict__ P, float* __restrict__ out, float* __restrict__ st,
    const float* __restrict__ g, const float* __restrict__ bb,
    int M, int C, int rowsPerBlock, int nBlocks, int zs, int writeOut) {
  __shared__ float sh[512];
  __shared__ int isLast;
  size_t MN = (size_t)M * C;
  int t = threadIdx.x;
  int r0 = blockIdx.x * rowsPerBlock;
  int r1 = min(M, r0 + rowsPerBlock);
  if (C >= 256) {
    for (int c = t; c < C; c += 256) {
      float s = 0.f, ss = 0.f;
      for (int r = r0; r < r1; ++r) {
        size_t idx = (size_t)r * C + c;
        float v = P[idx];
        for (int z = 1; z < zs; ++z) v += P[(size_t)z * MN + idx];
        if (writeOut) out[idx] = v;
        s += v; ss += v * v;
      }
      atomicAdd(&st[c], s); atomicAdd(&st[512 + c], ss);
    }
  } else {
    int rpb = 256 / C;
    int c = t % C; int ro = t / C;
    float s = 0.f, ss = 0.f;
    for (int r = r0 + ro; r < r1; r += rpb) {
      size_t idx = (size_t)r * C + c;
      float v = P[idx];
      for (int z = 1; z < zs; ++z) v += P[(size_t)z * MN + idx];
      if (writeOut) out[idx] = v;
      s += v; ss += v * v;
    }
    sh[t] = s; sh[256 + t] = ss;
    __syncthreads();
    if (ro == 0) {
      for (int k = 1; k < rpb; ++k) { s += sh[k * C + c]; ss += sh[256 + k * C + c]; }
      atomicAdd(&st[c], s); atomicAdd(&st[512 + c], ss);
    }
  }
  __syncthreads();
  if (t == 0) {
    __threadfence();
    unsigned old = atomicAdd((unsigned int*)(st + 2048), 1u);
    isLast = (old == (unsigned)(nBlocks - 1)) ? 1 : 0;
  }
  __syncthreads();
  if (isLast) {
    for (int c = t; c < C; c += 256) {
      float s = atomicAdd(&st[c], 0.f);
      float ss = atomicAdd(&st[512 + c], 0.f);
      float mean = s / (float)M;
      float var = ss / (float)M - mean * mean;
      if (var < 0.f) var = 0.f;
      float inv = 1.0f / sqrtf(var + 1e-5f);
      float scv = g[c] * inv;
      st[1024 + c] = scv;
      st[1536 + c] = bb[c] - mean * scv;
    }
  }
}

// -------- permuted 2x2 max pool with fused BN+ReLU on inputs --------
__global__ void pool_kernel(const float* __restrict__ in, const float* __restrict__ stp,
                            float* __restrict__ out,
                            const int* __restrict__ perm, const int* __restrict__ nperm,
                            int B, int H, int C, int total) {
  int i = blockIdx.x * blockDim.x + threadIdx.x;
  if (i >= total) return;
  int oH = H / 2; int oHW = oH * oH; int HW = H * H;
  int c = i % C; int j = (i / C) % oHW; int b = i / (C * oHW);
  float sc = stp[c], sh = stp[512 + c];
  int q = min(max(nperm[j], 0), oHW - 1);
  int qy = q / oH, qx = q % oH;
  float m = 0.f;
#pragma unroll
  for (int dy = 0; dy < 2; ++dy)
#pragma unroll
    for (int dx = 0; dx < 2; ++dx) {
      int p = min(max(perm[(2 * qy + dy) * H + (2 * qx + dx)], 0), HW - 1);
      float v = in[((size_t)b * HW + p) * C + c];
      v = fmaxf(v * sc + sh, 0.f);
      m = fmaxf(m, v);
    }
  out[((size_t)b * oHW + j) * C + c] = m;
}

// target >= 512 four-wave blocks; kPerZ multiple of 32
static inline void pick_split4(int gx, int gy, int Kp, int& zs, int& kPerZ) {
  int gxy = gx * gy;
  zs = 1;
  if (gxy < 512) {
    zs = (512 + gxy - 1) / gxy;
    int maxz = Kp / 32; if (maxz < 1) maxz = 1;
    if (zs > maxz) zs = maxz;
  }
  kPerZ = (((Kp + zs - 1) / zs) + 31) & ~31;
  zs = (Kp + kPerZ - 1) / kPerZ;
}

// FC split: target >= 512 blocks, zs capped at 32
static inline void pick_splitFC(int gy, int K, int& zs, int& kPerZ) {
  zs = (512 + gy - 1) / gy;
  int maxz = K / 32; if (maxz < 1) maxz = 1;
  if (zs > maxz) zs = maxz;
  if (zs > 32) zs = 32;
  kPerZ = (((K + zs - 1) / zs) + 31) & ~31;
  zs = (K + kPerZ - 1) / kPerZ;
}

static inline int ilog2(int v) { int l = 0; while ((1 << l) < v) ++l; return l; }

extern "C" void kernel_launch(void* const* d_in, const int* in_sizes, int n_in,
                              void* d_out, int out_size, void* d_ws, size_t ws_size,
                              hipStream_t stream) {
  const int Ci[13]  = {3, 64, 64, 128, 128, 256, 256, 256, 512, 512, 512, 512, 512};
  const int CoA[13] = {64, 64, 128, 128, 256, 256, 256, 512, 512, 512, 512, 512, 512};
  const int Rr[13]  = {32, 32, 16, 16, 8, 8, 8, 4, 4, 4, 2, 2, 2};
  const int poolAfter[13] = {-1, 0, -1, 1, -1, -1, 2, -1, -1, 3, -1, -1, 4};
  const size_t wOff[13] = {0, 2048, 38912, 112640, 260096, 555008, 1144832, 1734656,
                           2914304, 5273600, 7632896, 9992192, 12351488};
  const int WT_TOTAL = 14710784;
  const int B = 32;
  const int ST = 2304;

  size_t cursor = 0;
  auto alloc = [&](size_t bytes) {
    void* p = (char*)d_ws + cursor;
    cursor += (bytes + 255) & ~(size_t)255;
    return p;
  };
  float* stats = (float*)alloc((size_t)13 * ST * 4);
  u16*   fcPh  = (u16*)alloc((size_t)32 * 4096 * 2);
  u16*   fcPl  = (u16*)alloc((size_t)32 * 4096 * 2);
  float* A0    = (float*)alloc((size_t)2097152 * 4);
  float* A1    = (float*)alloc((size_t)2097152 * 4);
  u16*   WTh   = (u16*)alloc((size_t)WT_TOTAL * 2);
  u16*   WTl   = (u16*)alloc((size_t)WT_TOTAL * 2);
  float* Pbuf  = (float*)alloc((size_t)8388608 * 4);   // 32 MB split-K partials
  u16*   Sh    = (u16*)alloc((size_t)9437184 * 2);     // S: max = L3 (8192x1152)
  u16*   Sl    = (u16*)alloc((size_t)9437184 * 2);
  (void)in_sizes; (void)n_in; (void)out_size;

  hipMemsetAsync(stats, 0, (size_t)13 * ST * 4, stream);

  {
    int total = B * 3 * 1024;
    nchw2nhwc_kernel<<<(total + 255) / 256, 256, 0, stream>>>(
        (const float*)d_in[0], A0, B, 3, 1024);
  }
  wtc_all_v2<<<(PAIR_TOTAL + PAD_TOTAL + 255) / 256, 256, 0, stream>>>(
      (const float*)d_in[2],  (const float*)d_in[7],  (const float*)d_in[12],
      (const float*)d_in[17], (const float*)d_in[22], (const float*)d_in[27],
      (const float*)d_in[32], (const float*)d_in[37], (const float*)d_in[42],
      (const float*)d_in[47], (const float*)d_in[52], (const float*)d_in[57],
      (const float*)d_in[62], WTh, WTl);

  float* cur = A0;
  float* oth = A1;
  int needBN = 0;
  float* stp = nullptr;

  for (int l = 0; l < 13; ++l) {
    int C = Ci[l], N = CoA[l], H = Rr[l];
    int M = B * H * H, K = 9 * C, Kp = (K + 31) & ~31;
    const float* offp = (const float*)d_in[1 + l * 5 + 0];
    const float* gp   = (const float*)d_in[1 + l * 5 + 3];
    const float* bbp  = (const float*)d_in[1 + l * 5 + 4];
    float* st = stats + (size_t)l * ST;

    int gx = M / 64, gy = N / 64;
    int zs, kPerZ;
    pick_split4(gx, gy, Kp, zs, kPerZ);
    float* gemmOut;

    if (l == 0) {
      // C=3: scalar sampler into S, then plain tiled GEMM (gx=512 -> zs=1)
      gemmOut = (zs > 1) ? Pbuf : oth;
      int work = M * Kp;
      deform_sample_scalar<<<(work + 255) / 256, 256, 0, stream>>>(
          cur, offp, Sh, Sl, 0, M, B, H, H, C, Kp);
      mfma_gemm_tiled<<<dim3(gx, gy, zs), 256, 0, stream>>>(
          Sh, Sl, WTh + wOff[l], WTl + wOff[l], gemmOut, M, N, Kp, kPerZ, zs > 1 ? 1 : 0);
    } else if (gy == 1) {
      // L1 (N=64): fused sampling+GEMM. Force zs=2 for grid fill (512 -> 1024 blocks
      // = 4 blocks/CU); sampling work partitions exactly across z (no duplication).
      zs = 2; kPerZ = Kp / 2;           // Kp=576 -> 288, multiple of 32
      gemmOut = Pbuf;
      int lw_ = ilog2(H), lhw_ = 2 * lw_, lc_ = ilog2(C);
      mfma_gemm_fused<<<dim3(gx, 1, zs), 256, 0, stream>>>(
          cur, stp, needBN, offp, WTh + wOff[l], WTl + wOff[l],
          gemmOut, M, N, Kp, kPerZ, 1, H, H, C, lc_, lhw_, lw_);
    } else {
      // standalone sampler (full parallelism, coalesced) + tiled GEMM
      gemmOut = (zs > 1) ? Pbuf : oth;
      int work = M * 9 * (C >> 3);
      deform_sample_v3<<<(work + 255) / 256, 256, 0, stream>>>(
          cur, stp, needBN, offp, Sh, Sl, 0, M, B, H, H, C, Kp);
      mfma_gemm_tiled<<<dim3(gx, gy, zs), 256, 0, stream>>>(
          Sh, Sl, WTh + wOff[l], WTl + wOff[l], gemmOut, M, N, Kp, kPerZ, zs > 1 ? 1 : 0);
    }

    // adaptive rows/block: keep grid >= ~128 blocks even for tiny M
    int rowsPer = M / 128;
    if (rowsPer < 1) rowsPer = 1;
    if (rowsPer > 64) rowsPer = 64;
    int nB = (M + rowsPer - 1) / rowsPer;
    if (zs > 1)
      bn_stats_fused<<<nB, 256, 0, stream>>>(Pbuf, oth, st, gp, bbp,
                                             M, N, rowsPer, nB, zs, 1);
    else
      bn_stats_fused<<<nB, 256, 0, stream>>>(oth, oth, st, gp, bbp,
                                             M, N, rowsPer, nB, 1, 0);

    if (poolAfter[l] >= 0) {
      int pi = poolAfter[l];
      const int* perm  = (const int*)d_in[66 + pi * 2];
      const int* nperm = (const int*)d_in[66 + pi * 2 + 1];
      int oH = H / 2;
      int total = B * oH * oH * N;
      pool_kernel<<<(total + 255) / 256, 256, 0, stream>>>(oth, st + 1024, cur,
                                                           perm, nperm, B, H, N, total);
      needBN = 0; stp = nullptr;
    } else {
      float* t = cur; cur = oth; oth = t;
      needBN = 1; stp = st + 1024;
    }
  }

  // FC head: cur = [32, 512] fp32 (BN+ReLU applied by final pool)
  const float* fw1 = (const float*)d_in[76]; const float* fb1 = (const float*)d_in[77];
  const float* fw2 = (const float*)d_in[78]; const float* fb2 = (const float*)d_in[79];
  const float* fw3 = (const float*)d_in[80]; const float* fb3 = (const float*)d_in[81];
  {
    int zs, kPerZ;
    act_convert<<<(32 * 512 + 255) / 256, 256, 0, stream>>>(cur, fcPh, fcPl, 32 * 512);
    // FC1: 32x4096x512
    pick_splitFC(64, 512, zs, kPerZ);
    mfma_gemm_fc4<<<dim3(1, 64, zs), 256, 0, stream>>>(fcPh, fcPl, fw1, Pbuf,
                                                       4096, 512, kPerZ);
    fc_reduce_convert<<<(32 * 4096 + 255) / 256, 256, 0, stream>>>(
        Pbuf, fb1, fcPh, fcPl, 32 * 4096, 4096, zs);
    // FC2: 32x4096x4096
    pick_splitFC(64, 4096, zs, kPerZ);
    mfma_gemm_fc4<<<dim3(1, 64, zs), 256, 0, stream>>>(fcPh, fcPl, fw2, Pbuf,
                                                       4096, 4096, kPerZ);
    fc_reduce_convert<<<(32 * 4096 + 255) / 256, 256, 0, stream>>>(
        Pbuf, fb2, fcPh, fcPl, 32 * 4096, 4096, zs);
    // FC3: 32x100x4096
    pick_splitFC(2, 4096, zs, kPerZ);
    mfma_gemm_fc4<<<dim3(1, 2, zs), 256, 0, stream>>>(fcPh, fcPl, fw3, Pbuf,
                                                      100, 4096, kPerZ);
    fc_reduce_out<<<(3200 + 255) / 256, 256, 0, stream>>>(
        Pbuf, fb3, (float*)d_out, 3200, 100, zs);
  }
}